// Round 2
// baseline (2390.997 us; speedup 1.0000x reference)
//
#include <hip/hip_runtime.h>

#define NN 200000
#define QQ 4096
#define GG 64
#define EE 262144
#define EE0 131072
#define KK 10
#define QKp (QQ*KK)

// ---- workspace layout (float offsets), total ~61.5 MB ----
#define o_M      0                      // 5 x 64x64: M00,M01,M10,M11b,M01T
#define o_pA1    20480
#define o_pA2    (o_pA1+262144)
#define o_pB1    (o_pA2+262144)
#define o_pB2    (o_pB1+262144)
#define o_sQ     (o_pB2+262144)
#define o_segmax (o_sQ+4096)
#define o_segsum (o_segmax+200000)
#define o_has    (o_segsum+200000)
#define o_elog   (o_has+200000)         // logits -> ebuf -> trans (in place)
#define o_rm22   (o_elog+262144)
#define o_target (o_rm22+262144)
#define o_psrc   (o_target+262144)
#define o_pdst   (o_psrc+40960)
#define o_pt     (o_pdst+40960)
#define o_g      (o_pt+40960)           // one 51MB node array; reused as agg0
#define o_end    (o_g+12800000)         // 15,382,464 floats

__device__ __forceinline__ float dot4(float4 a, float4 b){
  return a.x*b.x + a.y*b.y + a.z*b.z + a.w*b.w;
}
// order-preserving float <-> uint encode for atomicMax on signed floats
__device__ __forceinline__ unsigned fenc(float f){
  unsigned u = __float_as_uint(f);
  return (u & 0x80000000u) ? ~u : (u | 0x80000000u);
}
__device__ __forceinline__ float fdec(unsigned e){
  return (e & 0x80000000u) ? __uint_as_float(e ^ 0x80000000u) : __uint_as_float(~e);
}

// M[m][i][j] = sum_k A[k][aoff+i] * B[k][boff+j]
// m: 0=M00(Wq0,Wk0) 1=M01(Wq0,Wk1) 2=M10(Wq1,Wk0) 3=M11b(Wq1,Wk1) 4=M01T(Wk1,Wq0)
__global__ void compute_M_k(const float* __restrict__ Wq, const float* __restrict__ Wk,
                            float* __restrict__ M){
  __shared__ float wa[64][64], wb[64][64];
  int m = blockIdx.x;
  const float* A = (m==4) ? Wk : Wq;
  const float* B = (m==4) ? Wq : Wk;
  int aoff = (m==2 || m==3 || m==4) ? 64 : 0;
  int boff = (m==1 || m==3) ? 64 : 0;
  int t = threadIdx.x;
  int j = t & 63, g = t >> 6;
  float acc[16];
  #pragma unroll
  for (int ii=0; ii<16; ii++) acc[ii]=0.f;
  for (int k0=0; k0<256; k0+=64){
    for (int s=0; s<16; s++){
      int kk = g*16 + s;
      wa[kk][j] = A[(k0+kk)*256 + aoff + j];
      wb[kk][j] = B[(k0+kk)*256 + boff + j];
    }
    __syncthreads();
    for (int kk=0; kk<64; kk++){
      float bv = wb[kk][j];
      #pragma unroll
      for (int ii=0; ii<16; ii++) acc[ii] += wa[kk][g*16+ii]*bv;
    }
    __syncthreads();
  }
  for (int ii=0; ii<16; ii++) M[m*4096 + (g*16+ii)*64 + j] = acc[ii];
}

// per-query: c = Wq[:,128:256]@[qst;qr], d = Wk[:,128:256]@[qst;qr]
// pA1 = Wq[:,0:64]^T d, pA2 = Wq[:,64:128]^T d, pB1 = Wk[:,0:64]^T c, pB2 = Wk[:,64:128]^T c, sQ = c.d
__global__ void per_query_k(const float* __restrict__ Wq, const float* __restrict__ Wk,
                            const float* __restrict__ QST, const float* __restrict__ QR,
                            float* __restrict__ pA1, float* __restrict__ pA2,
                            float* __restrict__ pB1, float* __restrict__ pB2,
                            float* __restrict__ sQ){
  __shared__ float qst[64], qr[64], c[256], d[256];
  int q = blockIdx.x, t = threadIdx.x;
  if (t < 64) qst[t] = QST[q*64 + t];
  else if (t < 128) qr[t-64] = QR[q*64 + (t-64)];
  __syncthreads();
  const float* wqr = Wq + t*256;
  const float* wkr = Wk + t*256;
  float ac=0.f, ad=0.f;
  for (int k=0;k<64;k++){
    float s_ = qst[k], r_ = qr[k];
    ac += wqr[128+k]*s_ + wqr[192+k]*r_;
    ad += wkr[128+k]*s_ + wkr[192+k]*r_;
  }
  c[t]=ac; d[t]=ad;
  __syncthreads();
  int grp = t>>6, i = t&63;
  float acc = 0.f;
  if (grp==0){ for (int tt=0;tt<256;tt++) acc += Wq[tt*256 + i]*d[tt];       pA1[q*64+i]=acc; }
  else if (grp==1){ for (int tt=0;tt<256;tt++) acc += Wq[tt*256 + 64 + i]*d[tt]; pA2[q*64+i]=acc; }
  else if (grp==2){ for (int tt=0;tt<256;tt++) acc += Wk[tt*256 + i]*c[tt];      pB1[q*64+i]=acc; }
  else            { for (int tt=0;tt<256;tt++) acc += Wk[tt*256 + 64 + i]*c[tt]; pB2[q*64+i]=acc; }
  if (t==0){
    float s_=0.f;
    for (int tt=0;tt<256;tt++) s_ += c[tt]*d[tt];
    sQ[q]=s_;
  }
}

// O[r] = W @ X[r]   (W 64x64 row-major, thread-uniform -> scalar-cached)
__global__ void matvec64_k(const float* __restrict__ X, const float* __restrict__ W,
                           float* __restrict__ O, int rows){
  int r = blockIdx.x*blockDim.x + threadIdx.x;
  if (r >= rows) return;
  const float4* Xv = (const float4*)(X + (size_t)r*64);
  float4 x[16];
  #pragma unroll
  for (int jj=0;jj<16;jj++) x[jj] = Xv[jj];
  const float4* Wv = (const float4*)W;
  float4* Ov = (float4*)(O + (size_t)r*64);
  for (int i0=0; i0<16; i0++){
    float a[4];
    #pragma unroll
    for (int ii=0; ii<4; ii++){
      float s=0.f;
      #pragma unroll
      for (int jj=0;jj<16;jj++) s += dot4(Wv[(i0*4+ii)*16+jj], x[jj]);
      a[ii]=s;
    }
    Ov[i0] = make_float4(a[0],a[1],a[2],a[3]);
  }
}

// out[r] = X[r]^T M X[r]  (quadratic form, thread per row)
__global__ void quadform_k(const float* __restrict__ X, const float* __restrict__ W,
                           float* __restrict__ O, int rows){
  int r = blockIdx.x*blockDim.x + threadIdx.x;
  if (r >= rows) return;
  const float4* Xv = (const float4*)(X + (size_t)r*64);
  float4 x[16];
  #pragma unroll
  for (int jj=0;jj<16;jj++) x[jj] = Xv[jj];
  const float4* Wv = (const float4*)W;
  float acc = 0.f;
  #pragma unroll
  for (int i0=0; i0<16; i0++){
    float xi[4] = {x[i0].x, x[i0].y, x[i0].z, x[i0].w};
    #pragma unroll
    for (int ii=0; ii<4; ii++){
      float s=0.f;
      #pragma unroll
      for (int jj=0;jj<16;jj++) s += dot4(Wv[(i0*4+ii)*16+jj], x[jj]);
      acc += xi[ii]*s;
    }
  }
  O[r] = acc;
}

__global__ void linear_leaky_k(const float* __restrict__ X, const float* __restrict__ W,
                               const float* __restrict__ bias, float* __restrict__ O, int rows){
  int r = blockIdx.x*blockDim.x + threadIdx.x;
  if (r >= rows) return;
  const float4* Xv = (const float4*)(X + (size_t)r*64);
  float4 x[16];
  #pragma unroll
  for (int jj=0;jj<16;jj++) x[jj] = Xv[jj];
  const float4* Wv = (const float4*)W;
  float4* Ov = (float4*)(O + (size_t)r*64);
  for (int i0=0; i0<16; i0++){
    float a[4];
    #pragma unroll
    for (int ii=0; ii<4; ii++){
      float s = bias[i0*4+ii];
      #pragma unroll
      for (int jj=0;jj<16;jj++) s += dot4(Wv[(i0*4+ii)*16+jj], x[jj]);
      a[ii] = (s >= 0.f) ? s : 0.01f*s;
    }
    Ov[i0] = make_float4(a[0],a[1],a[2],a[3]);
  }
}

// wave per edge: logits[e] = hs.pA1[q] + hd.pB1[q] + r.(pA2+pB2)[q] + sQ[q] + rm22[e] (+gamma*prior)
__global__ void passQ_k(const int* __restrict__ edges, const float* __restrict__ H,
                        const float* __restrict__ REL,
                        const float* __restrict__ pA1, const float* __restrict__ pA2,
                        const float* __restrict__ pB1, const float* __restrict__ pB2,
                        const float* __restrict__ sQ, const float* __restrict__ rm22,
                        const float* __restrict__ prior, const float* __restrict__ gamma_p,
                        float* __restrict__ logits, int nE){
  int w = (blockIdx.x*blockDim.x + threadIdx.x) >> 6;
  int lane = threadIdx.x & 63;
  if (w >= nE) return;
  int q = edges[(size_t)w*8 + 0];
  int s = edges[(size_t)w*8 + 6];
  int d = edges[(size_t)w*8 + 7];
  size_t qo = (size_t)q*64 + lane;
  float hs = H[(size_t)s*64 + lane];
  float hd = H[(size_t)d*64 + lane];
  float rr = REL[(size_t)w*64 + lane];
  float acc = hs*pA1[qo] + hd*pB1[qo] + rr*(pA2[qo]+pB2[qo]);
  #pragma unroll
  for (int off=32; off>0; off>>=1) acc += __shfl_xor(acc, off, 64);
  if (lane == 0){
    float lg = acc + sQ[q] + rm22[w];
    if (prior) lg += gamma_p[0]*prior[w];
    logits[w] = lg;
  }
}

// wave per edge: mode0: logits[e]+=H[s].g[d]; mode1: logits[e]+=REL[e].g[d];
// mode2: logits[e]+=REL[e].g[s], then atomicMax(segmax[s])
__global__ void dot_k(const int* __restrict__ edges, const float* __restrict__ H,
                      const float* __restrict__ REL, const float* __restrict__ g,
                      float* __restrict__ logits, unsigned* __restrict__ segmax,
                      int mode, int nE){
  int w = (blockIdx.x*blockDim.x + threadIdx.x) >> 6;
  int lane = threadIdx.x & 63;
  if (w >= nE) return;
  int s = edges[(size_t)w*8 + 6];
  int d = edges[(size_t)w*8 + 7];
  float a, b;
  if (mode == 0){ a = H[(size_t)s*64 + lane];   b = g[(size_t)d*64 + lane]; }
  else if (mode == 1){ a = REL[(size_t)w*64 + lane]; b = g[(size_t)d*64 + lane]; }
  else { a = REL[(size_t)w*64 + lane]; b = g[(size_t)s*64 + lane]; }
  float acc = a*b;
  #pragma unroll
  for (int off=32; off>0; off>>=1) acc += __shfl_xor(acc, off, 64);
  if (lane == 0){
    float lg = logits[w] + acc;
    logits[w] = lg;
    if (mode == 2) atomicMax(&segmax[s], fenc(lg));
  }
}

__global__ void expsum_k(const int* __restrict__ edges, float* __restrict__ elog,
                         const unsigned* __restrict__ segmax,
                         float* __restrict__ segsum, int* __restrict__ has, int nE){
  int e = blockIdx.x*blockDim.x + threadIdx.x;
  if (e >= nE) return;
  int s = edges[(size_t)e*8 + 6];
  float m = fdec(segmax[s]);
  float ev = expf(elog[e] - m);
  elog[e] = ev;
  atomicAdd(&segsum[s], ev);
  if (has) has[s] = 1;
}

__global__ void trans_k(const int* __restrict__ edges, float* __restrict__ elog,
                        const float* __restrict__ segsum, const float* __restrict__ vscore,
                        float* __restrict__ target, int nE){
  int e = blockIdx.x*blockDim.x + threadIdx.x;
  if (e >= nE) return;
  int s = edges[(size_t)e*8 + 6];
  float t = elog[e] / segsum[s];
  elog[e] = t;
  if (target) target[e] = t * vscore[s];
}

// one wave per query row of 64; exact lax.top_k semantics: descending value, lower index on ties
__global__ void topk_k(const float* __restrict__ target, const float* __restrict__ trans,
                       const int* __restrict__ edges, const float* __restrict__ vscore,
                       float* __restrict__ out_score, float* __restrict__ out_pruned,
                       float* __restrict__ out_orig, int* __restrict__ psrc, int* __restrict__ pdst,
                       float* __restrict__ pt, int* __restrict__ has){
  int q = blockIdx.x*4 + (threadIdx.x>>6);
  int lane = threadIdx.x & 63;
  if (q >= QQ) return;
  float myv = target[(size_t)q*GG + lane];
  for (int j=0;j<KK;j++){
    float v = myv; int idx = lane;
    #pragma unroll
    for (int off=32; off>0; off>>=1){
      float ov = __shfl_xor(v, off, 64);
      int oi = __shfl_xor(idx, off, 64);
      if (ov > v || (ov == v && oi < idx)){ v = ov; idx = oi; }
    }
    if (lane == idx){
      myv = -__builtin_inff();
      int orig = q*GG + idx;
      out_orig[q*KK + j] = (float)orig;
      int s = edges[(size_t)orig*8 + 6];
      int d = edges[(size_t)orig*8 + 7];
      #pragma unroll
      for (int c=0;c<8;c++) out_pruned[((size_t)q*KK+j)*8 + c] = (float)edges[(size_t)orig*8 + c];
      float t = trans[orig];
      float ss = vscore[s];
      atomicAdd(&out_score[d], t*ss);
      psrc[q*KK+j] = s; pdst[q*KK+j] = d; pt[q*KK+j] = t;
      has[s] = 1;
    }
  }
}

// wave per pruned edge: agg[src] += t * H[dst]
__global__ void scatter_pruned_k(const int* __restrict__ psrc, const int* __restrict__ pdst,
                                 const float* __restrict__ pt, const float* __restrict__ H,
                                 float* __restrict__ agg){
  int p = (blockIdx.x*blockDim.x + threadIdx.x) >> 6;
  int lane = threadIdx.x & 63;
  if (p >= QKp) return;
  int s = psrc[p], d = pdst[p];
  float t = pt[p];
  atomicAdd(&agg[(size_t)s*64 + lane], t * H[(size_t)d*64 + lane]);
}

// wave per edge: agg[src] += trans * H[dst]
__global__ void scatter_edges_k(const int* __restrict__ edges, const float* __restrict__ trans,
                                const float* __restrict__ H, float* __restrict__ agg, int nE){
  int e = (blockIdx.x*blockDim.x + threadIdx.x) >> 6;
  int lane = threadIdx.x & 63;
  if (e >= nE) return;
  int s = edges[(size_t)e*8 + 6];
  int d = edges[(size_t)e*8 + 7];
  atomicAdd(&agg[(size_t)s*64 + lane], trans[e] * H[(size_t)d*64 + lane]);
}

// if node has no outgoing edge: dst[i] = src[i]  (RATIO==0 semantics)
__global__ void fixup_copy_k(const int* __restrict__ has, const float* __restrict__ src,
                             float* __restrict__ dstbuf){
  int i = blockIdx.x*blockDim.x + threadIdx.x;
  if (i >= NN*64) return;
  int v = i >> 6;
  if (!has[v]) dstbuf[i] = src[i];
}

extern "C" void kernel_launch(void* const* d_in, const int* in_sizes, int n_in,
                              void* d_out, int out_size, void* d_ws, size_t ws_size,
                              hipStream_t stream){
  const float* vscore    = (const float*)d_in[0];
  const float* node_repr = (const float*)d_in[1];
  const float* rel0      = (const float*)d_in[2];
  const float* rel1      = (const float*)d_in[3];
  const float* prior     = (const float*)d_in[4];
  const float* qst       = (const float*)d_in[5];
  const float* qre       = (const float*)d_in[6];
  const float* Wq        = (const float*)d_in[7];
  const float* Wk        = (const float*)d_in[8];
  const float* Wlin      = (const float*)d_in[9];
  const float* blin      = (const float*)d_in[10];
  const float* gamma     = (const float*)d_in[11];
  const int*   edges0    = (const int*)d_in[12];
  const int*   edges1    = (const int*)d_in[13];

  float* ws = (float*)d_ws;
  float* M      = ws + o_M;
  float* pA1    = ws + o_pA1;
  float* pA2    = ws + o_pA2;
  float* pB1    = ws + o_pB1;
  float* pB2    = ws + o_pB2;
  float* sQv    = ws + o_sQ;
  unsigned* segmax = (unsigned*)(ws + o_segmax);
  float* segsum = ws + o_segsum;
  int*   has    = (int*)(ws + o_has);
  float* elog   = ws + o_elog;          // logits -> ebuf -> trans in place
  float* rm22   = ws + o_rm22;
  float* target = ws + o_target;
  int*   psrc   = (int*)(ws + o_psrc);
  int*   pdst   = (int*)(ws + o_pdst);
  float* pt     = ws + o_pt;
  float* gbuf   = ws + o_g;             // per-node 64-vec; reused as agg0

  float* out_score  = (float*)d_out;
  float* out_repr   = out_score + NN;            // upd1 lives here between layers
  float* out_pruned = out_repr + (size_t)NN*64;
  float* out_orig   = out_pruned + (size_t)QKp*8;

  const float* M00  = M + 0;
  const float* M01  = M + 4096;   // (unused directly; M01T used)
  const float* M10  = M + 8192;
  const float* M11b = M + 12288;
  const float* M01T = M + 16384;
  (void)M01;

  // zero: segmax+segsum+has (contiguous), out_score + out_repr (upd1)
  hipMemsetAsync(ws + o_segmax, 0, (size_t)600000*4, stream);
  hipMemsetAsync(out_score, 0, (size_t)(NN + (size_t)NN*64)*4, stream);

  compute_M_k<<<5,256,0,stream>>>(Wq, Wk, M);
  per_query_k<<<QQ,256,0,stream>>>(Wq, Wk, qst, qre, pA1, pA2, pB1, pB2, sQv);

  // ---- layer 1 (edges1, H=node_repr, rel1, prior) ----
  quadform_k<<<EE/256,256,0,stream>>>(rel1, M11b, rm22, EE);
  passQ_k<<<EE/4,256,0,stream>>>(edges1, node_repr, rel1, pA1,pA2,pB1,pB2, sQv, rm22,
                                 prior, gamma, elog, EE);
  matvec64_k<<<(NN+255)/256,256,0,stream>>>(node_repr, M00, gbuf, NN);
  dot_k<<<EE/4,256,0,stream>>>(edges1, node_repr, rel1, gbuf, elog, segmax, 0, EE);
  matvec64_k<<<(NN+255)/256,256,0,stream>>>(node_repr, M10, gbuf, NN);
  dot_k<<<EE/4,256,0,stream>>>(edges1, node_repr, rel1, gbuf, elog, segmax, 1, EE);
  matvec64_k<<<(NN+255)/256,256,0,stream>>>(node_repr, M01T, gbuf, NN);
  dot_k<<<EE/4,256,0,stream>>>(edges1, node_repr, rel1, gbuf, elog, segmax, 2, EE);
  expsum_k<<<EE/256,256,0,stream>>>(edges1, elog, segmax, segsum, nullptr, EE);
  trans_k<<<EE/256,256,0,stream>>>(edges1, elog, segsum, vscore, target, EE);
  topk_k<<<QQ/4,256,0,stream>>>(target, elog, edges1, vscore, out_score, out_pruned, out_orig,
                                psrc, pdst, pt, has);
  scatter_pruned_k<<<(QKp*64)/256,256,0,stream>>>(psrc, pdst, pt, node_repr, out_repr);
  fixup_copy_k<<<(NN*64+255)/256,256,0,stream>>>(has, node_repr, out_repr);

  // ---- layer 0 (edges0, H=upd1(=out_repr), rel0, no prior) ----
  hipMemsetAsync(ws + o_segmax, 0, (size_t)600000*4, stream);   // segmax+segsum+has
  quadform_k<<<EE0/256,256,0,stream>>>(rel0, M11b, rm22, EE0);
  passQ_k<<<EE0/4,256,0,stream>>>(edges0, out_repr, rel0, pA1,pA2,pB1,pB2, sQv, rm22,
                                  nullptr, nullptr, elog, EE0);
  matvec64_k<<<(NN+255)/256,256,0,stream>>>(out_repr, M00, gbuf, NN);
  dot_k<<<EE0/4,256,0,stream>>>(edges0, out_repr, rel0, gbuf, elog, segmax, 0, EE0);
  matvec64_k<<<(NN+255)/256,256,0,stream>>>(out_repr, M10, gbuf, NN);
  dot_k<<<EE0/4,256,0,stream>>>(edges0, out_repr, rel0, gbuf, elog, segmax, 1, EE0);
  matvec64_k<<<(NN+255)/256,256,0,stream>>>(out_repr, M01T, gbuf, NN);
  dot_k<<<EE0/4,256,0,stream>>>(edges0, out_repr, rel0, gbuf, elog, segmax, 2, EE0);
  expsum_k<<<EE0/256,256,0,stream>>>(edges0, elog, segmax, segsum, has, EE0);
  trans_k<<<EE0/256,256,0,stream>>>(edges0, elog, segsum, vscore, nullptr, EE0);
  hipMemsetAsync(gbuf, 0, (size_t)NN*64*4, stream);             // agg0 reuses gbuf
  scatter_edges_k<<<(EE0*64)/256,256,0,stream>>>(edges0, elog, out_repr, gbuf, EE0);
  fixup_copy_k<<<(NN*64+255)/256,256,0,stream>>>(has, out_repr, gbuf);
  linear_leaky_k<<<(NN+255)/256,256,0,stream>>>(gbuf, Wlin, blin, out_repr, NN);
}

// Round 3
// 1413.079 us; speedup vs baseline: 1.6920x; 1.6920x over previous
//
#include <hip/hip_runtime.h>

#define NN 200000
#define QQ 4096
#define GG 64
#define EE 262144
#define EE0 131072
#define KK 10
#define QKp (QQ*KK)

// ---- workspace layout (float offsets), total ~61.7 MB ----
#define o_M      0                      // 4 x 64x64: M00,M10,M01T,M11b
#define o_GpT    16384                  // 128x384 repacked per-query matrix
#define o_P      65536                  // Q x 256: [pA1|pA2|pB1|pB2] per query
#define o_sQ     1114112
#define o_segmax 1118208
#define o_segsum 1318208
#define o_has    1518208
#define o_elog   1718208                // logits -> ebuf -> trans (in place)
#define o_rm22   1980352
#define o_target 2242496
#define o_psrc   2504640
#define o_pdst   2545600
#define o_pt     2586560
#define o_g      2627520                // 51MB node buffer; holds G first, then matvec out / agg0
#define o_end    (o_g+12800000)

__device__ __forceinline__ float dot4(float4 a, float4 b){
  return a.x*b.x + a.y*b.y + a.z*b.z + a.w*b.w;
}
// order-preserving float <-> uint encode for atomicMax on signed floats
__device__ __forceinline__ unsigned fenc(float f){
  unsigned u = __float_as_uint(f);
  return (u & 0x80000000u) ? ~u : (u | 0x80000000u);
}
__device__ __forceinline__ float fdec(unsigned e){
  return (e & 0x80000000u) ? __uint_as_float(e ^ 0x80000000u) : __uint_as_float(~e);
}

// G[i][j] = sum_k Wq[k][i] * Wk[k][j]   (full 256x256 = Wq^T Wk), 16 blocks of 64x64
__global__ void computeG_k(const float* __restrict__ Wq, const float* __restrict__ Wk,
                           float* __restrict__ G){
  __shared__ float wa[64][64], wb[64][64];
  int m = blockIdx.x;
  int aoff = (m>>2)*64, boff = (m&3)*64;
  int t = threadIdx.x;
  int j = t & 63, g = t >> 6;
  float acc[16];
  #pragma unroll
  for (int ii=0; ii<16; ii++) acc[ii]=0.f;
  for (int k0=0; k0<256; k0+=64){
    for (int s=0; s<16; s++){
      int kk = g*16 + s;
      wa[kk][j] = Wq[(k0+kk)*256 + aoff + j];
      wb[kk][j] = Wk[(k0+kk)*256 + boff + j];
    }
    __syncthreads();
    for (int kk=0; kk<64; kk++){
      float bv = wb[kk][j];
      #pragma unroll
      for (int ii=0; ii<16; ii++) acc[ii] += wa[kk][g*16+ii]*bv;
    }
    __syncthreads();
  }
  for (int ii=0; ii<16; ii++) G[(aoff + g*16+ii)*256 + boff + j] = acc[ii];
}

// Build M00/M10/M01T/M11b (4x4096) and GpT (128x384) from G.
// GpT[j][i] = (i<128) ? G[i][128+j] : G[128+j][i-128]
__global__ void repack_k(const float* __restrict__ G, float* __restrict__ M,
                         float* __restrict__ GpT){
  int t = blockIdx.x*256 + threadIdx.x;   // 0..65535
  if (t < 16384){
    int m = t >> 12, r = (t >> 6) & 63, c = t & 63;
    float v;
    if (m==0)      v = G[r*256 + c];            // M00 = G[0:64,0:64]
    else if (m==1) v = G[(64+r)*256 + c];       // M10 = G[64:128,0:64]
    else if (m==2) v = G[c*256 + 64 + r];       // M01T = G[0:64,64:128]^T
    else           v = G[(64+r)*256 + 64 + c];  // M11b = G[64:128,64:128]
    M[t] = v;
  } else {
    int u = t - 16384;                    // 0..49151 = 128*384
    int j = u / 384, i = u - j*384;
    GpT[u] = (i < 128) ? G[i*256 + 128 + j] : G[(128+j)*256 + (i-128)];
  }
}

// wave per query: P[q][0:256] = Gp @ [qst;qr], sQ[q] = x^T G22 x
// lane l accumulates P outputs 4l..4l+3 (float4), lanes<32 also quadform partials
__global__ void pq_k(const float* __restrict__ QST, const float* __restrict__ QR,
                     const float* __restrict__ GpT, float* __restrict__ P,
                     float* __restrict__ sQ){
  __shared__ float xs[4][128];
  int wv = threadIdx.x >> 6, lane = threadIdx.x & 63;
  int q = blockIdx.x*4 + wv;
  xs[wv][lane]      = QST[(size_t)q*64 + lane];
  xs[wv][64 + lane] = QR[(size_t)q*64 + lane];
  __syncthreads();
  float4 accP = {0.f,0.f,0.f,0.f};
  float4 accY = {0.f,0.f,0.f,0.f};
  for (int j=0; j<128; j++){
    float xv = xs[wv][j];
    float4 gpv = ((const float4*)(GpT + j*384))[lane];
    accP.x += gpv.x*xv; accP.y += gpv.y*xv; accP.z += gpv.z*xv; accP.w += gpv.w*xv;
    if (lane < 32){
      float4 gyv = ((const float4*)(GpT + j*384 + 256))[lane];
      accY.x += gyv.x*xv; accY.y += gyv.y*xv; accY.z += gyv.z*xv; accY.w += gyv.w*xv;
    }
  }
  ((float4*)(P + (size_t)q*256))[lane] = accP;
  float sq = 0.f;
  if (lane < 32){
    sq = accY.x*xs[wv][4*lane] + accY.y*xs[wv][4*lane+1]
       + accY.z*xs[wv][4*lane+2] + accY.w*xs[wv][4*lane+3];
  }
  #pragma unroll
  for (int off=32; off>0; off>>=1) sq += __shfl_xor(sq, off, 64);
  if (lane == 0) sQ[q] = sq;
}

// O[r] = W @ X[r]   (W 64x64 row-major, wave-uniform -> scalar-cached)
__global__ void matvec64_k(const float* __restrict__ X, const float* __restrict__ W,
                           float* __restrict__ O, int rows){
  int r = blockIdx.x*blockDim.x + threadIdx.x;
  if (r >= rows) return;
  const float4* Xv = (const float4*)(X + (size_t)r*64);
  float4 x[16];
  #pragma unroll
  for (int jj=0;jj<16;jj++) x[jj] = Xv[jj];
  const float4* Wv = (const float4*)W;
  float4* Ov = (float4*)(O + (size_t)r*64);
  for (int i0=0; i0<16; i0++){
    float a[4];
    #pragma unroll
    for (int ii=0; ii<4; ii++){
      float s=0.f;
      #pragma unroll
      for (int jj=0;jj<16;jj++) s += dot4(Wv[(i0*4+ii)*16+jj], x[jj]);
      a[ii]=s;
    }
    Ov[i0] = make_float4(a[0],a[1],a[2],a[3]);
  }
}

// out[r] = X[r]^T M X[r]  (quadratic form, thread per row)
__global__ void quadform_k(const float* __restrict__ X, const float* __restrict__ W,
                           float* __restrict__ O, int rows){
  int r = blockIdx.x*blockDim.x + threadIdx.x;
  if (r >= rows) return;
  const float4* Xv = (const float4*)(X + (size_t)r*64);
  float4 x[16];
  #pragma unroll
  for (int jj=0;jj<16;jj++) x[jj] = Xv[jj];
  const float4* Wv = (const float4*)W;
  float acc = 0.f;
  #pragma unroll
  for (int i0=0; i0<16; i0++){
    float xi[4] = {x[i0].x, x[i0].y, x[i0].z, x[i0].w};
    #pragma unroll
    for (int ii=0; ii<4; ii++){
      float s=0.f;
      #pragma unroll
      for (int jj=0;jj<16;jj++) s += dot4(Wv[(i0*4+ii)*16+jj], x[jj]);
      acc += xi[ii]*s;
    }
  }
  O[r] = acc;
}

__global__ void linear_leaky_k(const float* __restrict__ X, const float* __restrict__ W,
                               const float* __restrict__ bias, float* __restrict__ O, int rows){
  int r = blockIdx.x*blockDim.x + threadIdx.x;
  if (r >= rows) return;
  const float4* Xv = (const float4*)(X + (size_t)r*64);
  float4 x[16];
  #pragma unroll
  for (int jj=0;jj<16;jj++) x[jj] = Xv[jj];
  const float4* Wv = (const float4*)W;
  float4* Ov = (float4*)(O + (size_t)r*64);
  for (int i0=0; i0<16; i0++){
    float a[4];
    #pragma unroll
    for (int ii=0; ii<4; ii++){
      float s = bias[i0*4+ii];
      #pragma unroll
      for (int jj=0;jj<16;jj++) s += dot4(Wv[(i0*4+ii)*16+jj], x[jj]);
      a[ii] = (s >= 0.f) ? s : 0.01f*s;
    }
    Ov[i0] = make_float4(a[0],a[1],a[2],a[3]);
  }
}

// wave per edge: logits[e] = hs.pA1 + hd.pB1 + r.(pA2+pB2) + sQ[q] + rm22[e] (+gamma*prior)
// P per-q layout: [pA1(64) | pA2(64) | pB1(64) | pB2(64)]
__global__ void passQ_k(const int* __restrict__ edges, const float* __restrict__ H,
                        const float* __restrict__ REL, const float* __restrict__ P,
                        const float* __restrict__ sQ, const float* __restrict__ rm22,
                        const float* __restrict__ prior, const float* __restrict__ gamma_p,
                        float* __restrict__ logits, int nE){
  int w = (blockIdx.x*blockDim.x + threadIdx.x) >> 6;
  int lane = threadIdx.x & 63;
  if (w >= nE) return;
  int q = edges[(size_t)w*8 + 0];
  int s = edges[(size_t)w*8 + 6];
  int d = edges[(size_t)w*8 + 7];
  const float* Pq = P + (size_t)q*256;
  float hs = H[(size_t)s*64 + lane];
  float hd = H[(size_t)d*64 + lane];
  float rr = REL[(size_t)w*64 + lane];
  float acc = hs*Pq[lane] + hd*Pq[128+lane] + rr*(Pq[64+lane]+Pq[192+lane]);
  #pragma unroll
  for (int off=32; off>0; off>>=1) acc += __shfl_xor(acc, off, 64);
  if (lane == 0){
    float lg = acc + sQ[q] + rm22[w];
    if (prior) lg += gamma_p[0]*prior[w];
    logits[w] = lg;
  }
}

// wave per edge: mode0: logits[e]+=H[s].g[d]; mode1: logits[e]+=REL[e].g[d];
// mode2: logits[e]+=REL[e].g[s], then atomicMax(segmax[s])
__global__ void dot_k(const int* __restrict__ edges, const float* __restrict__ H,
                      const float* __restrict__ REL, const float* __restrict__ g,
                      float* __restrict__ logits, unsigned* __restrict__ segmax,
                      int mode, int nE){
  int w = (blockIdx.x*blockDim.x + threadIdx.x) >> 6;
  int lane = threadIdx.x & 63;
  if (w >= nE) return;
  int s = edges[(size_t)w*8 + 6];
  int d = edges[(size_t)w*8 + 7];
  float a, b;
  if (mode == 0){ a = H[(size_t)s*64 + lane];   b = g[(size_t)d*64 + lane]; }
  else if (mode == 1){ a = REL[(size_t)w*64 + lane]; b = g[(size_t)d*64 + lane]; }
  else { a = REL[(size_t)w*64 + lane]; b = g[(size_t)s*64 + lane]; }
  float acc = a*b;
  #pragma unroll
  for (int off=32; off>0; off>>=1) acc += __shfl_xor(acc, off, 64);
  if (lane == 0){
    float lg = logits[w] + acc;
    logits[w] = lg;
    if (mode == 2) atomicMax(&segmax[s], fenc(lg));
  }
}

__global__ void expsum_k(const int* __restrict__ edges, float* __restrict__ elog,
                         const unsigned* __restrict__ segmax,
                         float* __restrict__ segsum, int* __restrict__ has, int nE){
  int e = blockIdx.x*blockDim.x + threadIdx.x;
  if (e >= nE) return;
  int s = edges[(size_t)e*8 + 6];
  float m = fdec(segmax[s]);
  float ev = expf(elog[e] - m);
  elog[e] = ev;
  atomicAdd(&segsum[s], ev);
  if (has) has[s] = 1;
}

__global__ void trans_k(const int* __restrict__ edges, float* __restrict__ elog,
                        const float* __restrict__ segsum, const float* __restrict__ vscore,
                        float* __restrict__ target, int nE){
  int e = blockIdx.x*blockDim.x + threadIdx.x;
  if (e >= nE) return;
  int s = edges[(size_t)e*8 + 6];
  float t = elog[e] / segsum[s];
  elog[e] = t;
  if (target) target[e] = t * vscore[s];
}

// one wave per query row of 64; exact lax.top_k semantics: descending value, lower index on ties
__global__ void topk_k(const float* __restrict__ target, const float* __restrict__ trans,
                       const int* __restrict__ edges, const float* __restrict__ vscore,
                       float* __restrict__ out_score, float* __restrict__ out_pruned,
                       float* __restrict__ out_orig, int* __restrict__ psrc, int* __restrict__ pdst,
                       float* __restrict__ pt, int* __restrict__ has){
  int q = blockIdx.x*4 + (threadIdx.x>>6);
  int lane = threadIdx.x & 63;
  if (q >= QQ) return;
  float myv = target[(size_t)q*GG + lane];
  for (int j=0;j<KK;j++){
    float v = myv; int idx = lane;
    #pragma unroll
    for (int off=32; off>0; off>>=1){
      float ov = __shfl_xor(v, off, 64);
      int oi = __shfl_xor(idx, off, 64);
      if (ov > v || (ov == v && oi < idx)){ v = ov; idx = oi; }
    }
    if (lane == idx){
      myv = -__builtin_inff();
      int orig = q*GG + idx;
      out_orig[q*KK + j] = (float)orig;
      int s = edges[(size_t)orig*8 + 6];
      int d = edges[(size_t)orig*8 + 7];
      #pragma unroll
      for (int c=0;c<8;c++) out_pruned[((size_t)q*KK+j)*8 + c] = (float)edges[(size_t)orig*8 + c];
      float t = trans[orig];
      float ss = vscore[s];
      atomicAdd(&out_score[d], t*ss);
      psrc[q*KK+j] = s; pdst[q*KK+j] = d; pt[q*KK+j] = t;
      has[s] = 1;
    }
  }
}

// wave per pruned edge: agg[src] += t * H[dst]
__global__ void scatter_pruned_k(const int* __restrict__ psrc, const int* __restrict__ pdst,
                                 const float* __restrict__ pt, const float* __restrict__ H,
                                 float* __restrict__ agg){
  int p = (blockIdx.x*blockDim.x + threadIdx.x) >> 6;
  int lane = threadIdx.x & 63;
  if (p >= QKp) return;
  int s = psrc[p], d = pdst[p];
  float t = pt[p];
  atomicAdd(&agg[(size_t)s*64 + lane], t * H[(size_t)d*64 + lane]);
}

// wave per edge: agg[src] += trans * H[dst]
__global__ void scatter_edges_k(const int* __restrict__ edges, const float* __restrict__ trans,
                                const float* __restrict__ H, float* __restrict__ agg, int nE){
  int e = (blockIdx.x*blockDim.x + threadIdx.x) >> 6;
  int lane = threadIdx.x & 63;
  if (e >= nE) return;
  int s = edges[(size_t)e*8 + 6];
  int d = edges[(size_t)e*8 + 7];
  atomicAdd(&agg[(size_t)s*64 + lane], trans[e] * H[(size_t)d*64 + lane]);
}

// if node has no outgoing edge: dst[i] = src[i]  (RATIO==0 semantics)
__global__ void fixup_copy_k(const int* __restrict__ has, const float* __restrict__ src,
                             float* __restrict__ dstbuf){
  int i = blockIdx.x*blockDim.x + threadIdx.x;
  if (i >= NN*64) return;
  int v = i >> 6;
  if (!has[v]) dstbuf[i] = src[i];
}

extern "C" void kernel_launch(void* const* d_in, const int* in_sizes, int n_in,
                              void* d_out, int out_size, void* d_ws, size_t ws_size,
                              hipStream_t stream){
  const float* vscore    = (const float*)d_in[0];
  const float* node_repr = (const float*)d_in[1];
  const float* rel0      = (const float*)d_in[2];
  const float* rel1      = (const float*)d_in[3];
  const float* prior     = (const float*)d_in[4];
  const float* qst       = (const float*)d_in[5];
  const float* qre       = (const float*)d_in[6];
  const float* Wq        = (const float*)d_in[7];
  const float* Wk        = (const float*)d_in[8];
  const float* Wlin      = (const float*)d_in[9];
  const float* blin      = (const float*)d_in[10];
  const float* gamma     = (const float*)d_in[11];
  const int*   edges0    = (const int*)d_in[12];
  const int*   edges1    = (const int*)d_in[13];

  float* ws = (float*)d_ws;
  float* M      = ws + o_M;
  float* GpT    = ws + o_GpT;
  float* P      = ws + o_P;
  float* sQv    = ws + o_sQ;
  unsigned* segmax = (unsigned*)(ws + o_segmax);
  float* segsum = ws + o_segsum;
  int*   has    = (int*)(ws + o_has);
  float* elog   = ws + o_elog;          // logits -> ebuf -> trans in place
  float* rm22   = ws + o_rm22;
  float* target = ws + o_target;
  int*   psrc   = (int*)(ws + o_psrc);
  int*   pdst   = (int*)(ws + o_pdst);
  float* pt     = ws + o_pt;
  float* gbuf   = ws + o_g;             // G first, then per-node matvec out / agg0

  float* out_score  = (float*)d_out;
  float* out_repr   = out_score + NN;            // upd1 lives here between layers
  float* out_pruned = out_repr + (size_t)NN*64;
  float* out_orig   = out_pruned + (size_t)QKp*8;

  const float* M00  = M + 0;
  const float* M10  = M + 4096;
  const float* M01T = M + 8192;
  const float* M11b = M + 12288;

  // zero: segmax+segsum+has (contiguous), out_score + out_repr (upd1)
  hipMemsetAsync(ws + o_segmax, 0, (size_t)600000*4, stream);
  hipMemsetAsync(out_score, 0, (size_t)(NN + (size_t)NN*64)*4, stream);

  // G staged in gbuf (consumed by repack before gbuf is reused by matvec)
  computeG_k<<<16,256,0,stream>>>(Wq, Wk, gbuf);
  repack_k<<<256,256,0,stream>>>(gbuf, M, GpT);
  pq_k<<<QQ/4,256,0,stream>>>(qst, qre, GpT, P, sQv);

  // ---- layer 1 (edges1, H=node_repr, rel1, prior) ----
  quadform_k<<<EE/256,256,0,stream>>>(rel1, M11b, rm22, EE);
  passQ_k<<<EE/4,256,0,stream>>>(edges1, node_repr, rel1, P, sQv, rm22,
                                 prior, gamma, elog, EE);
  matvec64_k<<<(NN+255)/256,256,0,stream>>>(node_repr, M00, gbuf, NN);
  dot_k<<<EE/4,256,0,stream>>>(edges1, node_repr, rel1, gbuf, elog, segmax, 0, EE);
  matvec64_k<<<(NN+255)/256,256,0,stream>>>(node_repr, M10, gbuf, NN);
  dot_k<<<EE/4,256,0,stream>>>(edges1, node_repr, rel1, gbuf, elog, segmax, 1, EE);
  matvec64_k<<<(NN+255)/256,256,0,stream>>>(node_repr, M01T, gbuf, NN);
  dot_k<<<EE/4,256,0,stream>>>(edges1, node_repr, rel1, gbuf, elog, segmax, 2, EE);
  expsum_k<<<EE/256,256,0,stream>>>(edges1, elog, segmax, segsum, nullptr, EE);
  trans_k<<<EE/256,256,0,stream>>>(edges1, elog, segsum, vscore, target, EE);
  topk_k<<<QQ/4,256,0,stream>>>(target, elog, edges1, vscore, out_score, out_pruned, out_orig,
                                psrc, pdst, pt, has);
  scatter_pruned_k<<<(QKp*64)/256,256,0,stream>>>(psrc, pdst, pt, node_repr, out_repr);
  fixup_copy_k<<<(NN*64+255)/256,256,0,stream>>>(has, node_repr, out_repr);

  // ---- layer 0 (edges0, H=upd1(=out_repr), rel0, no prior) ----
  hipMemsetAsync(ws + o_segmax, 0, (size_t)600000*4, stream);   // segmax+segsum+has
  quadform_k<<<EE0/256,256,0,stream>>>(rel0, M11b, rm22, EE0);
  passQ_k<<<EE0/4,256,0,stream>>>(edges0, out_repr, rel0, P, sQv, rm22,
                                  nullptr, nullptr, elog, EE0);
  matvec64_k<<<(NN+255)/256,256,0,stream>>>(out_repr, M00, gbuf, NN);
  dot_k<<<EE0/4,256,0,stream>>>(edges0, out_repr, rel0, gbuf, elog, segmax, 0, EE0);
  matvec64_k<<<(NN+255)/256,256,0,stream>>>(out_repr, M10, gbuf, NN);
  dot_k<<<EE0/4,256,0,stream>>>(edges0, out_repr, rel0, gbuf, elog, segmax, 1, EE0);
  matvec64_k<<<(NN+255)/256,256,0,stream>>>(out_repr, M01T, gbuf, NN);
  dot_k<<<EE0/4,256,0,stream>>>(edges0, out_repr, rel0, gbuf, elog, segmax, 2, EE0);
  expsum_k<<<EE0/256,256,0,stream>>>(edges0, elog, segmax, segsum, has, EE0);
  trans_k<<<EE0/256,256,0,stream>>>(edges0, elog, segsum, vscore, nullptr, EE0);
  hipMemsetAsync(gbuf, 0, (size_t)NN*64*4, stream);             // agg0 reuses gbuf
  scatter_edges_k<<<(EE0*64)/256,256,0,stream>>>(edges0, elog, out_repr, gbuf, EE0);
  fixup_copy_k<<<(NN*64+255)/256,256,0,stream>>>(has, out_repr, gbuf);
  linear_leaky_k<<<(NN+255)/256,256,0,stream>>>(gbuf, Wlin, blin, out_repr, NN);
}

// Round 4
// 1365.009 us; speedup vs baseline: 1.7516x; 1.0352x over previous
//
#include <hip/hip_runtime.h>

#define NN 200000
#define QQ 4096
#define GG 64
#define EE 262144
#define EE0 131072
#define KK 10
#define QKp (QQ*KK)
#define PITCH 68    // floats; %4==0 for float4 alignment, breaks 64-stride bank conflicts

// ---- workspace layout (float offsets), total ~61.7 MB ----
#define o_M      0                      // 4 x 64x64: M00,M10,M01T,M11b
#define o_GpT    16384                  // 128x384 repacked per-query matrix
#define o_P      65536                  // Q x 256: [pA1|pA2|pB1|pB2] per query
#define o_sQ     1114112
#define o_segmax 1118208
#define o_segsum 1318208
#define o_has    1518208
#define o_elog   1718208                // logits -> ebuf -> trans (in place)
#define o_rm22   1980352
#define o_target 2242496
#define o_psrc   2504640
#define o_pdst   2545600
#define o_pt     2586560
#define o_g      2627520                // 51MB node buffer; holds G first, then matvec out / agg0
#define o_end    (o_g+12800000)

__device__ __forceinline__ float dot4(float4 a, float4 b){
  return a.x*b.x + a.y*b.y + a.z*b.z + a.w*b.w;
}
// order-preserving float <-> uint encode for atomicMax on signed floats
__device__ __forceinline__ unsigned fenc(float f){
  unsigned u = __float_as_uint(f);
  return (u & 0x80000000u) ? ~u : (u | 0x80000000u);
}
__device__ __forceinline__ float fdec(unsigned e){
  return (e & 0x80000000u) ? __uint_as_float(e ^ 0x80000000u) : __uint_as_float(~e);
}

// G[i][j] = sum_k Wq[k][i] * Wk[k][j]   (full 256x256 = Wq^T Wk), 16 blocks of 64x64
__global__ void computeG_k(const float* __restrict__ Wq, const float* __restrict__ Wk,
                           float* __restrict__ G){
  __shared__ float wa[64][64], wb[64][64];
  int m = blockIdx.x;
  int aoff = (m>>2)*64, boff = (m&3)*64;
  int t = threadIdx.x;
  int j = t & 63, g = t >> 6;
  float acc[16];
  #pragma unroll
  for (int ii=0; ii<16; ii++) acc[ii]=0.f;
  for (int k0=0; k0<256; k0+=64){
    for (int s=0; s<16; s++){
      int kk = g*16 + s;
      wa[kk][j] = Wq[(k0+kk)*256 + aoff + j];
      wb[kk][j] = Wk[(k0+kk)*256 + boff + j];
    }
    __syncthreads();
    for (int kk=0; kk<64; kk++){
      float bv = wb[kk][j];
      #pragma unroll
      for (int ii=0; ii<16; ii++) acc[ii] += wa[kk][g*16+ii]*bv;
    }
    __syncthreads();
  }
  for (int ii=0; ii<16; ii++) G[(aoff + g*16+ii)*256 + boff + j] = acc[ii];
}

// Build M00/M10/M01T/M11b (4x4096) and GpT (128x384) from G.
// GpT[j][i] = (i<128) ? G[i][128+j] : G[128+j][i-128]
__global__ void repack_k(const float* __restrict__ G, float* __restrict__ M,
                         float* __restrict__ GpT){
  int t = blockIdx.x*256 + threadIdx.x;   // 0..65535
  if (t < 16384){
    int m = t >> 12, r = (t >> 6) & 63, c = t & 63;
    float v;
    if (m==0)      v = G[r*256 + c];            // M00 = G[0:64,0:64]
    else if (m==1) v = G[(64+r)*256 + c];       // M10 = G[64:128,0:64]
    else if (m==2) v = G[c*256 + 64 + r];       // M01T = G[0:64,64:128]^T
    else           v = G[(64+r)*256 + 64 + c];  // M11b = G[64:128,64:128]
    M[t] = v;
  } else {
    int u = t - 16384;                    // 0..49151 = 128*384
    int j = u / 384, i = u - j*384;
    GpT[u] = (i < 128) ? G[i*256 + 128 + j] : G[(128+j)*256 + (i-128)];
  }
}

// wave per query: P[q][0:256] = Gp @ [qst;qr], sQ[q] = x^T G22 x
__global__ void pq_k(const float* __restrict__ QST, const float* __restrict__ QR,
                     const float* __restrict__ GpT, float* __restrict__ P,
                     float* __restrict__ sQ){
  __shared__ float xs[4][128];
  int wv = threadIdx.x >> 6, lane = threadIdx.x & 63;
  int q = blockIdx.x*4 + wv;
  xs[wv][lane]      = QST[(size_t)q*64 + lane];
  xs[wv][64 + lane] = QR[(size_t)q*64 + lane];
  __syncthreads();
  float4 accP = {0.f,0.f,0.f,0.f};
  float4 accY = {0.f,0.f,0.f,0.f};
  for (int j=0; j<128; j++){
    float xv = xs[wv][j];
    float4 gpv = ((const float4*)(GpT + j*384))[lane];
    accP.x += gpv.x*xv; accP.y += gpv.y*xv; accP.z += gpv.z*xv; accP.w += gpv.w*xv;
    if (lane < 32){
      float4 gyv = ((const float4*)(GpT + j*384 + 256))[lane];
      accY.x += gyv.x*xv; accY.y += gyv.y*xv; accY.z += gyv.z*xv; accY.w += gyv.w*xv;
    }
  }
  ((float4*)(P + (size_t)q*256))[lane] = accP;
  float sq = 0.f;
  if (lane < 32){
    sq = accY.x*xs[wv][4*lane] + accY.y*xs[wv][4*lane+1]
       + accY.z*xs[wv][4*lane+2] + accY.w*xs[wv][4*lane+3];
  }
  #pragma unroll
  for (int off=32; off>0; off>>=1) sq += __shfl_xor(sq, off, 64);
  if (lane == 0) sQ[q] = sq;
}

// O[r] = W @ X[r].  One wave (64 threads) per 64 rows; LDS-staged coalesced I/O.
// rows must be a multiple of 64; grid = rows/64.
__global__ __launch_bounds__(64) void matvec64_k(const float* __restrict__ X,
                                                 const float* __restrict__ W,
                                                 float* __restrict__ O){
  __shared__ float lds[64*PITCH];
  int lane = threadIdx.x;
  size_t base = (size_t)blockIdx.x * 64;
  const float4* Xg = (const float4*)(X + base*64);
  #pragma unroll
  for (int i=0;i<16;i++){
    int f = i*64 + lane;
    float4 v = Xg[f];
    *(float4*)(lds + (f>>4)*PITCH + (f&15)*4) = v;
  }
  __builtin_amdgcn_sched_barrier(0);
  float4 x[16];
  #pragma unroll
  for (int jj=0;jj<16;jj++) x[jj] = *(const float4*)(lds + lane*PITCH + jj*4);
  __builtin_amdgcn_sched_barrier(0);
  const float4* Wv = (const float4*)W;
  for (int i0=0; i0<16; i0++){
    float a[4];
    #pragma unroll
    for (int ii=0; ii<4; ii++){
      float s=0.f;
      #pragma unroll
      for (int jj=0;jj<16;jj++) s += dot4(Wv[(i0*4+ii)*16+jj], x[jj]);
      a[ii]=s;
    }
    *(float4*)(lds + lane*PITCH + i0*4) = make_float4(a[0],a[1],a[2],a[3]);
  }
  __builtin_amdgcn_sched_barrier(0);
  float4* Og = (float4*)(O + base*64);
  #pragma unroll
  for (int i=0;i<16;i++){
    int f = i*64 + lane;
    Og[f] = *(const float4*)(lds + (f>>4)*PITCH + (f&15)*4);
  }
}

// out[r] = X[r]^T M X[r].  One wave per 64 rows; LDS-staged coalesced loads.
__global__ __launch_bounds__(64) void quadform_k(const float* __restrict__ X,
                                                 const float* __restrict__ W,
                                                 float* __restrict__ O){
  __shared__ float lds[64*PITCH];
  int lane = threadIdx.x;
  size_t base = (size_t)blockIdx.x * 64;
  const float4* Xg = (const float4*)(X + base*64);
  #pragma unroll
  for (int i=0;i<16;i++){
    int f = i*64 + lane;
    float4 v = Xg[f];
    *(float4*)(lds + (f>>4)*PITCH + (f&15)*4) = v;
  }
  __builtin_amdgcn_sched_barrier(0);
  float4 x[16];
  #pragma unroll
  for (int jj=0;jj<16;jj++) x[jj] = *(const float4*)(lds + lane*PITCH + jj*4);
  const float4* Wv = (const float4*)W;
  float acc = 0.f;
  #pragma unroll
  for (int i0=0; i0<16; i0++){
    float xi[4] = {x[i0].x, x[i0].y, x[i0].z, x[i0].w};
    #pragma unroll
    for (int ii=0; ii<4; ii++){
      float s=0.f;
      #pragma unroll
      for (int jj=0;jj<16;jj++) s += dot4(Wv[(i0*4+ii)*16+jj], x[jj]);
      acc += xi[ii]*s;
    }
  }
  O[base + lane] = acc;
}

// O[r] = leaky_relu(W @ X[r] + b).  Same staging as matvec64_k.
__global__ __launch_bounds__(64) void linear_leaky_k(const float* __restrict__ X,
                                                     const float* __restrict__ W,
                                                     const float* __restrict__ bias,
                                                     float* __restrict__ O){
  __shared__ float lds[64*PITCH];
  int lane = threadIdx.x;
  size_t base = (size_t)blockIdx.x * 64;
  const float4* Xg = (const float4*)(X + base*64);
  #pragma unroll
  for (int i=0;i<16;i++){
    int f = i*64 + lane;
    float4 v = Xg[f];
    *(float4*)(lds + (f>>4)*PITCH + (f&15)*4) = v;
  }
  __builtin_amdgcn_sched_barrier(0);
  float4 x[16];
  #pragma unroll
  for (int jj=0;jj<16;jj++) x[jj] = *(const float4*)(lds + lane*PITCH + jj*4);
  __builtin_amdgcn_sched_barrier(0);
  const float4* Wv = (const float4*)W;
  for (int i0=0; i0<16; i0++){
    float a[4];
    #pragma unroll
    for (int ii=0; ii<4; ii++){
      float s = bias[i0*4+ii];
      #pragma unroll
      for (int jj=0;jj<16;jj++) s += dot4(Wv[(i0*4+ii)*16+jj], x[jj]);
      a[ii] = (s >= 0.f) ? s : 0.01f*s;
    }
    *(float4*)(lds + lane*PITCH + i0*4) = make_float4(a[0],a[1],a[2],a[3]);
  }
  __builtin_amdgcn_sched_barrier(0);
  float4* Og = (float4*)(O + base*64);
  #pragma unroll
  for (int i=0;i<16;i++){
    int f = i*64 + lane;
    Og[f] = *(const float4*)(lds + (f>>4)*PITCH + (f&15)*4);
  }
}

// wave per edge: logits[e] = hs.pA1 + hd.pB1 + r.(pA2+pB2) + sQ[q] + rm22[e] (+gamma*prior)
__global__ void passQ_k(const int* __restrict__ edges, const float* __restrict__ H,
                        const float* __restrict__ REL, const float* __restrict__ P,
                        const float* __restrict__ sQ, const float* __restrict__ rm22,
                        const float* __restrict__ prior, const float* __restrict__ gamma_p,
                        float* __restrict__ logits, int nE){
  int w = (blockIdx.x*blockDim.x + threadIdx.x) >> 6;
  int lane = threadIdx.x & 63;
  if (w >= nE) return;
  int q = edges[(size_t)w*8 + 0];
  int s = edges[(size_t)w*8 + 6];
  int d = edges[(size_t)w*8 + 7];
  const float* Pq = P + (size_t)q*256;
  float hs = H[(size_t)s*64 + lane];
  float hd = H[(size_t)d*64 + lane];
  float rr = REL[(size_t)w*64 + lane];
  float acc = hs*Pq[lane] + hd*Pq[128+lane] + rr*(Pq[64+lane]+Pq[192+lane]);
  #pragma unroll
  for (int off=32; off>0; off>>=1) acc += __shfl_xor(acc, off, 64);
  if (lane == 0){
    float lg = acc + sQ[q] + rm22[w];
    if (prior) lg += gamma_p[0]*prior[w];
    logits[w] = lg;
  }
}

// wave per edge: mode0: logits[e]+=H[s].g[d]; mode1: logits[e]+=REL[e].g[d];
// mode2: logits[e]+=REL[e].g[s], then atomicMax(segmax[s])
__global__ void dot_k(const int* __restrict__ edges, const float* __restrict__ H,
                      const float* __restrict__ REL, const float* __restrict__ g,
                      float* __restrict__ logits, unsigned* __restrict__ segmax,
                      int mode, int nE){
  int w = (blockIdx.x*blockDim.x + threadIdx.x) >> 6;
  int lane = threadIdx.x & 63;
  if (w >= nE) return;
  int s = edges[(size_t)w*8 + 6];
  int d = edges[(size_t)w*8 + 7];
  float a, b;
  if (mode == 0){ a = H[(size_t)s*64 + lane];   b = g[(size_t)d*64 + lane]; }
  else if (mode == 1){ a = REL[(size_t)w*64 + lane]; b = g[(size_t)d*64 + lane]; }
  else { a = REL[(size_t)w*64 + lane]; b = g[(size_t)s*64 + lane]; }
  float acc = a*b;
  #pragma unroll
  for (int off=32; off>0; off>>=1) acc += __shfl_xor(acc, off, 64);
  if (lane == 0){
    float lg = logits[w] + acc;
    logits[w] = lg;
    if (mode == 2) atomicMax(&segmax[s], fenc(lg));
  }
}

__global__ void expsum_k(const int* __restrict__ edges, float* __restrict__ elog,
                         const unsigned* __restrict__ segmax,
                         float* __restrict__ segsum, int* __restrict__ has, int nE){
  int e = blockIdx.x*blockDim.x + threadIdx.x;
  if (e >= nE) return;
  int s = edges[(size_t)e*8 + 6];
  float m = fdec(segmax[s]);
  float ev = expf(elog[e] - m);
  elog[e] = ev;
  atomicAdd(&segsum[s], ev);
  if (has) has[s] = 1;
}

__global__ void trans_k(const int* __restrict__ edges, float* __restrict__ elog,
                        const float* __restrict__ segsum, const float* __restrict__ vscore,
                        float* __restrict__ target, int nE){
  int e = blockIdx.x*blockDim.x + threadIdx.x;
  if (e >= nE) return;
  int s = edges[(size_t)e*8 + 6];
  float t = elog[e] / segsum[s];
  elog[e] = t;
  if (target) target[e] = t * vscore[s];
}

// one wave per query row of 64; exact lax.top_k semantics: descending value, lower index on ties
__global__ void topk_k(const float* __restrict__ target, const float* __restrict__ trans,
                       const int* __restrict__ edges, const float* __restrict__ vscore,
                       float* __restrict__ out_score, float* __restrict__ out_pruned,
                       float* __restrict__ out_orig, int* __restrict__ psrc, int* __restrict__ pdst,
                       float* __restrict__ pt, int* __restrict__ has){
  int q = blockIdx.x*4 + (threadIdx.x>>6);
  int lane = threadIdx.x & 63;
  if (q >= QQ) return;
  float myv = target[(size_t)q*GG + lane];
  for (int j=0;j<KK;j++){
    float v = myv; int idx = lane;
    #pragma unroll
    for (int off=32; off>0; off>>=1){
      float ov = __shfl_xor(v, off, 64);
      int oi = __shfl_xor(idx, off, 64);
      if (ov > v || (ov == v && oi < idx)){ v = ov; idx = oi; }
    }
    if (lane == idx){
      myv = -__builtin_inff();
      int orig = q*GG + idx;
      out_orig[q*KK + j] = (float)orig;
      int s = edges[(size_t)orig*8 + 6];
      int d = edges[(size_t)orig*8 + 7];
      #pragma unroll
      for (int c=0;c<8;c++) out_pruned[((size_t)q*KK+j)*8 + c] = (float)edges[(size_t)orig*8 + c];
      float t = trans[orig];
      float ss = vscore[s];
      atomicAdd(&out_score[d], t*ss);
      psrc[q*KK+j] = s; pdst[q*KK+j] = d; pt[q*KK+j] = t;
      has[s] = 1;
    }
  }
}

// dst[i] = has[node] ? 0 : src[i]   (replaces memset + fixup pass; float4 over rows)
__global__ void init_upd_k(const int* __restrict__ has, const float* __restrict__ src,
                           float* __restrict__ dst){
  int i = blockIdx.x*256 + threadIdx.x;     // float4 index; NN*16 total
  int v = i >> 4;
  float4 z = {0.f,0.f,0.f,0.f};
  ((float4*)dst)[i] = has[v] ? z : ((const float4*)src)[i];
}

// wave per pruned edge: agg[src] += t * H[dst]
__global__ void scatter_pruned_k(const int* __restrict__ psrc, const int* __restrict__ pdst,
                                 const float* __restrict__ pt, const float* __restrict__ H,
                                 float* __restrict__ agg){
  int p = (blockIdx.x*blockDim.x + threadIdx.x) >> 6;
  int lane = threadIdx.x & 63;
  if (p >= QKp) return;
  int s = psrc[p], d = pdst[p];
  float t = pt[p];
  atomicAdd(&agg[(size_t)s*64 + lane], t * H[(size_t)d*64 + lane]);
}

// wave per edge: agg[src] += trans * H[dst]
__global__ void scatter_edges_k(const int* __restrict__ edges, const float* __restrict__ trans,
                                const float* __restrict__ H, float* __restrict__ agg, int nE){
  int e = (blockIdx.x*blockDim.x + threadIdx.x) >> 6;
  int lane = threadIdx.x & 63;
  if (e >= nE) return;
  int s = edges[(size_t)e*8 + 6];
  int d = edges[(size_t)e*8 + 7];
  atomicAdd(&agg[(size_t)s*64 + lane], trans[e] * H[(size_t)d*64 + lane]);
}

extern "C" void kernel_launch(void* const* d_in, const int* in_sizes, int n_in,
                              void* d_out, int out_size, void* d_ws, size_t ws_size,
                              hipStream_t stream){
  const float* vscore    = (const float*)d_in[0];
  const float* node_repr = (const float*)d_in[1];
  const float* rel0      = (const float*)d_in[2];
  const float* rel1      = (const float*)d_in[3];
  const float* prior     = (const float*)d_in[4];
  const float* qst       = (const float*)d_in[5];
  const float* qre       = (const float*)d_in[6];
  const float* Wq        = (const float*)d_in[7];
  const float* Wk        = (const float*)d_in[8];
  const float* Wlin      = (const float*)d_in[9];
  const float* blin      = (const float*)d_in[10];
  const float* gamma     = (const float*)d_in[11];
  const int*   edges0    = (const int*)d_in[12];
  const int*   edges1    = (const int*)d_in[13];

  float* ws = (float*)d_ws;
  float* M      = ws + o_M;
  float* GpT    = ws + o_GpT;
  float* P      = ws + o_P;
  float* sQv    = ws + o_sQ;
  unsigned* segmax = (unsigned*)(ws + o_segmax);
  float* segsum = ws + o_segsum;
  int*   has    = (int*)(ws + o_has);
  float* elog   = ws + o_elog;          // logits -> ebuf -> trans in place
  float* rm22   = ws + o_rm22;
  float* target = ws + o_target;
  int*   psrc   = (int*)(ws + o_psrc);
  int*   pdst   = (int*)(ws + o_pdst);
  float* pt     = ws + o_pt;
  float* gbuf   = ws + o_g;             // G first, then per-node matvec out / agg0

  float* out_score  = (float*)d_out;
  float* out_repr   = out_score + NN;            // upd1 lives here between layers
  float* out_pruned = out_repr + (size_t)NN*64;
  float* out_orig   = out_pruned + (size_t)QKp*8;

  const float* M00  = M + 0;
  const float* M10  = M + 4096;
  const float* M01T = M + 8192;
  const float* M11b = M + 12288;

  // zero: segmax+segsum+has (contiguous), out_score
  hipMemsetAsync(ws + o_segmax, 0, (size_t)600000*4, stream);
  hipMemsetAsync(out_score, 0, (size_t)NN*4, stream);

  // G staged in gbuf (consumed by repack before gbuf is reused by matvec)
  computeG_k<<<16,256,0,stream>>>(Wq, Wk, gbuf);
  repack_k<<<256,256,0,stream>>>(gbuf, M, GpT);
  pq_k<<<QQ/4,256,0,stream>>>(qst, qre, GpT, P, sQv);

  // ---- layer 1 (edges1, H=node_repr, rel1, prior) ----
  quadform_k<<<EE/64,64,0,stream>>>(rel1, M11b, rm22);
  passQ_k<<<EE/4,256,0,stream>>>(edges1, node_repr, rel1, P, sQv, rm22,
                                 prior, gamma, elog, EE);
  matvec64_k<<<NN/64,64,0,stream>>>(node_repr, M00, gbuf);
  dot_k<<<EE/4,256,0,stream>>>(edges1, node_repr, rel1, gbuf, elog, segmax, 0, EE);
  matvec64_k<<<NN/64,64,0,stream>>>(node_repr, M10, gbuf);
  dot_k<<<EE/4,256,0,stream>>>(edges1, node_repr, rel1, gbuf, elog, segmax, 1, EE);
  matvec64_k<<<NN/64,64,0,stream>>>(node_repr, M01T, gbuf);
  dot_k<<<EE/4,256,0,stream>>>(edges1, node_repr, rel1, gbuf, elog, segmax, 2, EE);
  expsum_k<<<EE/256,256,0,stream>>>(edges1, elog, segmax, segsum, nullptr, EE);
  trans_k<<<EE/256,256,0,stream>>>(edges1, elog, segsum, vscore, target, EE);
  topk_k<<<QQ/4,256,0,stream>>>(target, elog, edges1, vscore, out_score, out_pruned, out_orig,
                                psrc, pdst, pt, has);
  init_upd_k<<<NN*16/256,256,0,stream>>>(has, node_repr, out_repr);
  scatter_pruned_k<<<(QKp*64)/256,256,0,stream>>>(psrc, pdst, pt, node_repr, out_repr);

  // ---- layer 0 (edges0, H=upd1(=out_repr), rel0, no prior) ----
  hipMemsetAsync(ws + o_segmax, 0, (size_t)600000*4, stream);   // segmax+segsum+has
  quadform_k<<<EE0/64,64,0,stream>>>(rel0, M11b, rm22);
  passQ_k<<<EE0/4,256,0,stream>>>(edges0, out_repr, rel0, P, sQv, rm22,
                                  nullptr, nullptr, elog, EE0);
  matvec64_k<<<NN/64,64,0,stream>>>(out_repr, M00, gbuf);
  dot_k<<<EE0/4,256,0,stream>>>(edges0, out_repr, rel0, gbuf, elog, segmax, 0, EE0);
  matvec64_k<<<NN/64,64,0,stream>>>(out_repr, M10, gbuf);
  dot_k<<<EE0/4,256,0,stream>>>(edges0, out_repr, rel0, gbuf, elog, segmax, 1, EE0);
  matvec64_k<<<NN/64,64,0,stream>>>(out_repr, M01T, gbuf);
  dot_k<<<EE0/4,256,0,stream>>>(edges0, out_repr, rel0, gbuf, elog, segmax, 2, EE0);
  expsum_k<<<EE0/256,256,0,stream>>>(edges0, elog, segmax, segsum, has, EE0);
  trans_k<<<EE0/256,256,0,stream>>>(edges0, elog, segsum, vscore, nullptr, EE0);
  init_upd_k<<<NN*16/256,256,0,stream>>>(has, out_repr, gbuf);  // agg0 reuses gbuf
  scatter_edges_k<<<(EE0*64)/256,256,0,stream>>>(edges0, elog, out_repr, gbuf, EE0);
  linear_leaky_k<<<NN/64,64,0,stream>>>(gbuf, Wlin, blin, out_repr);
}